// Round 1
// baseline (199.945 us; speedup 1.0000x reference)
//
#include <hip/hip_runtime.h>

typedef _Float16 half4 __attribute__((ext_vector_type(4)));
typedef float floatx4 __attribute__((ext_vector_type(4)));

// tanh(x) = 1 - 2/(e^{2x}+1), e^{2x} = 2^{x * 2*log2(e)}
__device__ __forceinline__ float tanh_fast(float x) {
    float t = __builtin_amdgcn_exp2f(x * 2.885390081777927f);
    return 1.0f - 2.0f * __builtin_amdgcn_rcpf(t + 1.0f);
}

struct NetW {
    float  W0c[4][4];  // layer-0 weights, cols 0..3 (live x channels), rows obase..obase+3
    float  c1[4];      // folded: b0[o] + W0[o][4:16] . extra
    half4  aW[3];      // layers 1..3 as MFMA A-fragments (W[o=lane&15][k=(lane>>4)*4+e])
    floatx4 bC[3];     // biases as MFMA C-fragments
    floatx4 wf;        // final layer weights for this lane's 4 features
    float  bff;
};

// One MLP eval for 16 batch cols (whole wave). Returns final scalar in ALL lanes.
__device__ __forceinline__ float eval_net(float x0, float x1, float x2, float x3,
                                          const NetW& w)
{
    half4 hb;
#pragma unroll
    for (int e = 0; e < 4; ++e) {
        float z = w.c1[e];
        z = fmaf(w.W0c[e][0], x0, z);
        z = fmaf(w.W0c[e][1], x1, z);
        z = fmaf(w.W0c[e][2], x2, z);
        z = fmaf(w.W0c[e][3], x3, z);
        hb[e] = (_Float16)tanh_fast(z);
    }
    // hidden layers 1,2: D(fp32) -> tanh -> f16 B-frag (layout identity, no shuffles)
#pragma unroll
    for (int L = 0; L < 2; ++L) {
        floatx4 d = __builtin_amdgcn_mfma_f32_16x16x16f16(w.aW[L], hb, w.bC[L], 0, 0, 0);
#pragma unroll
        for (int e = 0; e < 4; ++e) hb[e] = (_Float16)tanh_fast(d[e]);
    }
    // hidden layer 3: keep fp32, fuse final 16->1 dot
    floatx4 d = __builtin_amdgcn_mfma_f32_16x16x16f16(w.aW[2], hb, w.bC[2], 0, 0, 0);
    float f = 0.0f;
#pragma unroll
    for (int e = 0; e < 4; ++e) f = fmaf(tanh_fast(d[e]), w.wf[e], f);
    f += __shfl_xor(f, 16);
    f += __shfl_xor(f, 32);
    return f + w.bff;
}

__global__ __launch_bounds__(256, 4) void automaton_kernel(
    const float* __restrict__ x, const float* __restrict__ Ws,
    const float* __restrict__ bs, const float* __restrict__ Wf,
    const float* __restrict__ bf, const float* __restrict__ extra,
    float* __restrict__ out, int n_groups)
{
    const int tid   = blockIdx.x * blockDim.x + threadIdx.x;
    const int wave  = tid >> 6;
    const int lane  = threadIdx.x & 63;
    const int col   = lane & 15;   // batch column (which (b,n) group)
    const int sub   = lane >> 4;   // feature quad
    const int obase = sub * 4;

    NetW w;
    float ex[12];
#pragma unroll
    for (int j = 0; j < 12; ++j) ex[j] = extra[j];

    // Layer 0: keep live cols, fold extra into c1
#pragma unroll
    for (int e = 0; e < 4; ++e) {
        const float* row = Ws + (obase + e) * 16;
        floatx4 r0 = *(const floatx4*)(row);
        floatx4 r1 = *(const floatx4*)(row + 4);
        floatx4 r2 = *(const floatx4*)(row + 8);
        floatx4 r3 = *(const floatx4*)(row + 12);
#pragma unroll
        for (int j = 0; j < 4; ++j) w.W0c[e][j] = r0[j];
        float c = bs[obase + e];
#pragma unroll
        for (int j = 0; j < 4; ++j) c = fmaf(r1[j], ex[j], c);
#pragma unroll
        for (int j = 0; j < 4; ++j) c = fmaf(r2[j], ex[4 + j], c);
#pragma unroll
        for (int j = 0; j < 4; ++j) c = fmaf(r3[j], ex[8 + j], c);
        w.c1[e] = c;
    }

    // Hidden layers 1..3 as A-fragments + bias C-fragments
#pragma unroll
    for (int L = 0; L < 3; ++L) {
        floatx4 wr = *(const floatx4*)(Ws + (L + 1) * 256 + col * 16 + sub * 4);
        half4 a;
#pragma unroll
        for (int e = 0; e < 4; ++e) a[e] = (_Float16)wr[e];
        w.aW[L] = a;
        w.bC[L] = *(const floatx4*)(bs + (L + 1) * 16 + obase);
    }
    w.wf  = *(const floatx4*)(Wf + obase);
    w.bff = bf[0];

    const int g     = wave * 16 + col;
    const bool valid = (g < n_groups);
    const int gl    = valid ? g : (n_groups - 1);
    const float* xp = x + (size_t)gl * 104;   // 26 channels * 4 floats

    float acc = 0.0f;
    floatx4 xv = *(const floatx4*)(xp);
#pragma unroll 2
    for (int c = 0; c < 26; ++c) {
        floatx4 xn = (c < 25) ? *(const floatx4*)(xp + (c + 1) * 4) : xv;
        float f1 = eval_net(xv[0], xv[1], xv[2], xv[3], w);  // x1 = [x, extra]
        float f2 = eval_net(xv[2], xv[3], xv[0], xv[1], w);  // x2 = [x[2:],x[:2], extra]
        acc += tanh_fast(f1 - f2);
        xv = xn;
    }
    if (lane < 16 && valid)
        out[g] = acc * (0.05234482976098482f * 0.8f);
}

extern "C" void kernel_launch(void* const* d_in, const int* in_sizes, int n_in,
                              void* d_out, int out_size, void* d_ws, size_t ws_size,
                              hipStream_t stream) {
    const float* x  = (const float*)d_in[0];
    const float* Ws = (const float*)d_in[1];
    const float* bs = (const float*)d_in[2];
    const float* Wf = (const float*)d_in[3];
    const float* bf = (const float*)d_in[4];
    const float* ex = (const float*)d_in[5];
    float* out = (float*)d_out;

    const int n_groups = out_size;              // B*N = 262144
    const int waves    = (n_groups + 15) / 16;  // 16 groups per wave
    const int blocks   = (waves + 3) / 4;       // 4 waves per block
    automaton_kernel<<<blocks, 256, 0, stream>>>(x, Ws, bs, Wf, bf, ex, out, n_groups);
}

// Round 3
// 185.308 us; speedup vs baseline: 1.0790x; 1.0790x over previous
//
#include <hip/hip_runtime.h>

typedef __fp16   fp16x2  __attribute__((ext_vector_type(2)));
typedef _Float16 half4   __attribute__((ext_vector_type(4)));
typedef float    floatx4 __attribute__((ext_vector_type(4)));

// All pre-activations arrive pre-scaled by K = 2*log2(e), folded into weights.
// tanh(z) = 1 - 2/(2^(K*z) + 1)
__device__ __forceinline__ float act_pre(float a) {
    float t = __builtin_amdgcn_exp2f(a);
    float r = __builtin_amdgcn_rcpf(t + 1.0f);
    return fmaf(-2.0f, r, 1.0f);
}

__device__ __forceinline__ half4 mk4(fp16x2 lo, fp16x2 hi) {
    union { fp16x2 h2[2]; half4 h4; } u;
    u.h2[0] = lo; u.h2[1] = hi;
    return u.h4;
}

struct NetW {
    float   W0c[4][4];  // layer-0 live cols, pre-scaled by K
    float   c1[4];      // K * (b0 + W0[:,4:16] . extra)
    half4   aW[3];      // layers 1..3 A-frags, pre-scaled by K
    floatx4 bC[3];      // biases as C-frags, pre-scaled by K
    half4   aWf;        // final-layer weights K*Wf[k], replicated over rows
};

__global__ __launch_bounds__(256, 4) void automaton_kernel(
    const float* __restrict__ x, const float* __restrict__ Ws,
    const float* __restrict__ bs, const float* __restrict__ Wf,
    const float* __restrict__ bf, const float* __restrict__ extra,
    float* __restrict__ out, int n_groups)
{
    const float K = 2.885390081777927f;  // 2*log2(e)
    const int tid   = blockIdx.x * blockDim.x + threadIdx.x;
    const int wave  = tid >> 6;
    const int lane  = threadIdx.x & 63;
    const int col   = lane & 15;
    const int sub   = lane >> 4;
    const int obase = sub * 4;

    NetW w;
    float ex[12];
#pragma unroll
    for (int j = 0; j < 12; ++j) ex[j] = extra[j];

    // Layer 0: live cols (scaled by K), fold extra+bias into c1 (scaled by K)
#pragma unroll
    for (int e = 0; e < 4; ++e) {
        const float* row = Ws + (obase + e) * 16;
        floatx4 r0 = *(const floatx4*)(row);
        floatx4 r1 = *(const floatx4*)(row + 4);
        floatx4 r2 = *(const floatx4*)(row + 8);
        floatx4 r3 = *(const floatx4*)(row + 12);
#pragma unroll
        for (int j = 0; j < 4; ++j) w.W0c[e][j] = r0[j] * K;
        float c = bs[obase + e];
#pragma unroll
        for (int j = 0; j < 4; ++j) c = fmaf(r1[j], ex[j], c);
#pragma unroll
        for (int j = 0; j < 4; ++j) c = fmaf(r2[j], ex[4 + j], c);
#pragma unroll
        for (int j = 0; j < 4; ++j) c = fmaf(r3[j], ex[8 + j], c);
        w.c1[e] = c * K;
    }

    // Hidden layers 1..3 as A-frags + bias C-frags, all pre-scaled by K
#pragma unroll
    for (int L = 0; L < 3; ++L) {
        floatx4 wr = *(const floatx4*)(Ws + (L + 1) * 256 + col * 16 + obase);
        half4 a;
#pragma unroll
        for (int e = 0; e < 4; ++e) a[e] = (_Float16)(wr[e] * K);
        w.aW[L] = a;
        floatx4 bb = *(const floatx4*)(bs + (L + 1) * 16 + obase);
#pragma unroll
        for (int e = 0; e < 4; ++e) bb[e] *= K;
        w.bC[L] = bb;
    }
    {
        // Reduction MFMA: A[o,k] = K*Wf[k] for every o -> D = K*Wf.(t1-t2) in all lanes
        floatx4 wf = *(const floatx4*)(Wf + obase);
        half4 a;
#pragma unroll
        for (int e = 0; e < 4; ++e) a[e] = (_Float16)(wf[e] * K);
        w.aWf = a;
    }

    const int g      = wave * 16 + col;
    const bool valid = (g < n_groups);
    const int gl     = valid ? g : (n_groups - 1);
    const float* xp  = x + (size_t)gl * 104;   // 26 channels * 4 floats

    const floatx4 zeroC = {0.f, 0.f, 0.f, 0.f};
    float acc = 0.0f;
    floatx4 xv = *(const floatx4*)(xp);
#pragma unroll 2
    for (int c = 0; c < 26; ++c) {
        floatx4 xn = (c < 25) ? *(const floatx4*)(xp + (c + 1) * 4) : xv;

        // Layer 0 for both nets (net2 = rotated channels), f32 FMA
        half4 hb1, hb2;
        {
            float z1[4], z2[4];
#pragma unroll
            for (int e = 0; e < 4; ++e) {
                float a1 = w.c1[e];
                a1 = fmaf(w.W0c[e][0], xv[0], a1);
                a1 = fmaf(w.W0c[e][1], xv[1], a1);
                a1 = fmaf(w.W0c[e][2], xv[2], a1);
                a1 = fmaf(w.W0c[e][3], xv[3], a1);
                float a2 = w.c1[e];
                a2 = fmaf(w.W0c[e][0], xv[2], a2);
                a2 = fmaf(w.W0c[e][1], xv[3], a2);
                a2 = fmaf(w.W0c[e][2], xv[0], a2);
                a2 = fmaf(w.W0c[e][3], xv[1], a2);
                z1[e] = a1; z2[e] = a2;
            }
            hb1 = mk4(__builtin_amdgcn_cvt_pkrtz(act_pre(z1[0]), act_pre(z1[1])),
                      __builtin_amdgcn_cvt_pkrtz(act_pre(z1[2]), act_pre(z1[3])));
            hb2 = mk4(__builtin_amdgcn_cvt_pkrtz(act_pre(z2[0]), act_pre(z2[1])),
                      __builtin_amdgcn_cvt_pkrtz(act_pre(z2[2]), act_pre(z2[3])));
        }

        // Hidden layers 1,2: MFMA -> packed tanh -> f16 B-frag (layout identity)
#pragma unroll
        for (int L = 0; L < 2; ++L) {
            floatx4 d1 = __builtin_amdgcn_mfma_f32_16x16x16f16(w.aW[L], hb1, w.bC[L], 0, 0, 0);
            floatx4 d2 = __builtin_amdgcn_mfma_f32_16x16x16f16(w.aW[L], hb2, w.bC[L], 0, 0, 0);
            hb1 = mk4(__builtin_amdgcn_cvt_pkrtz(act_pre(d1[0]), act_pre(d1[1])),
                      __builtin_amdgcn_cvt_pkrtz(act_pre(d1[2]), act_pre(d1[3])));
            hb2 = mk4(__builtin_amdgcn_cvt_pkrtz(act_pre(d2[0]), act_pre(d2[1])),
                      __builtin_amdgcn_cvt_pkrtz(act_pre(d2[2]), act_pre(d2[3])));
        }

        // Hidden layer 3 + fused final 16->1 via reduction MFMA (bf cancels in f1-f2)
        {
            floatx4 d1 = __builtin_amdgcn_mfma_f32_16x16x16f16(w.aW[2], hb1, w.bC[2], 0, 0, 0);
            floatx4 d2 = __builtin_amdgcn_mfma_f32_16x16x16f16(w.aW[2], hb2, w.bC[2], 0, 0, 0);
            float s0 = act_pre(d1[0]) - act_pre(d2[0]);
            float s1 = act_pre(d1[1]) - act_pre(d2[1]);
            float s2 = act_pre(d1[2]) - act_pre(d2[2]);
            float s3 = act_pre(d1[3]) - act_pre(d2[3]);
            half4 sb = mk4(__builtin_amdgcn_cvt_pkrtz(s0, s1),
                           __builtin_amdgcn_cvt_pkrtz(s2, s3));
            floatx4 dr = __builtin_amdgcn_mfma_f32_16x16x16f16(w.aWf, sb, zeroC, 0, 0, 0);
            acc += act_pre(dr[0]);
        }
        xv = xn;
    }
    if (lane < 16 && valid)
        out[g] = acc * 0.041875863808787856f;  // ONE_OVER_DIFF_TOT * DIFF_Q
}

extern "C" void kernel_launch(void* const* d_in, const int* in_sizes, int n_in,
                              void* d_out, int out_size, void* d_ws, size_t ws_size,
                              hipStream_t stream) {
    const float* x  = (const float*)d_in[0];
    const float* Ws = (const float*)d_in[1];
    const float* bs = (const float*)d_in[2];
    const float* Wf = (const float*)d_in[3];
    const float* bf = (const float*)d_in[4];
    const float* ex = (const float*)d_in[5];
    float* out = (float*)d_out;

    const int n_groups = out_size;              // B*N = 262144
    const int waves    = (n_groups + 15) / 16;  // 16 groups per wave
    const int blocks   = (waves + 3) / 4;       // 4 waves per block
    automaton_kernel<<<blocks, 256, 0, stream>>>(x, Ws, bs, Wf, bf, ex, out, n_groups);
}